// Round 2
// baseline (3376.403 us; speedup 1.0000x reference)
//
#include <hip/hip_runtime.h>
#include <stdint.h>

#define NU 200000
#define NM 100000
#define DIM 64
#define SCAN_CHUNK 2048

// ---------------------------------------------------------------------------
// Detect whether edge index arrays are int64 or int32.
// If int64 (little-endian), every odd 32-bit word (high half) is 0 since
// indices < 200000. If int32, odd words are real indices; P(2048 all zero)~0.
__global__ void detect_idx_kernel(const unsigned int* __restrict__ words,
                                  int* __restrict__ flag) {
    __shared__ int nz;
    if (threadIdx.x == 0) nz = 0;
    __syncthreads();
    for (int i = threadIdx.x; i < 2048; i += blockDim.x)
        if (words[2 * i + 1] != 0u) nz = 1;
    __syncthreads();
    if (threadIdx.x == 0) *flag = (nz == 0) ? 1 : 0;   // 1 => int64
}

__device__ __forceinline__ int load_idx(const void* __restrict__ p, int e, int is64) {
    if (is64) return (int)((const long long*)p)[e];
    return ((const int*)p)[e];
}

// ---------------------------------------------------------------------------
// Degree histogram for both directions in one pass.
__global__ void count_kernel(const void* __restrict__ es, const void* __restrict__ ed,
                             const int* __restrict__ flag,
                             int* __restrict__ deg_u, int* __restrict__ deg_m, int nE) {
    const int is64 = *flag;
    const int stride = gridDim.x * blockDim.x;
    for (int e = blockIdx.x * blockDim.x + threadIdx.x; e < nE; e += stride) {
        int s = load_idx(es, e, is64);
        int d = load_idx(ed, e, is64);
        atomicAdd(&deg_u[s], 1);
        atomicAdd(&deg_m[d], 1);
    }
}

// ---------------------------------------------------------------------------
// Exclusive scan over n ints, 3 phases (chunk = 2048 = 256 thr x 8).
__global__ void scan_block_sums(const int* __restrict__ a, int* __restrict__ bsum, int n) {
    int base = blockIdx.x * SCAN_CHUNK + threadIdx.x * 8;
    int tot = 0;
#pragma unroll
    for (int k = 0; k < 8; ++k) { int i = base + k; if (i < n) tot += a[i]; }
    __shared__ int sc[256];
    sc[threadIdx.x] = tot;
    __syncthreads();
    for (int off = 128; off > 0; off >>= 1) {
        if (threadIdx.x < off) sc[threadIdx.x] += sc[threadIdx.x + off];
        __syncthreads();
    }
    if (threadIdx.x == 0) bsum[blockIdx.x] = sc[0];
}

__global__ void scan_bsum(int* __restrict__ bsum, int nb) {
    if (blockIdx.x == 0 && threadIdx.x == 0) {
        int acc = 0;
        for (int i = 0; i < nb; ++i) { int v = bsum[i]; bsum[i] = acc; acc += v; }
    }
}

// exclusive scan in place; also writes a[n] = nE
__global__ void scan_apply(int* __restrict__ a, const int* __restrict__ bsum, int n, int nE) {
    const int t = threadIdx.x;
    int base = blockIdx.x * SCAN_CHUNK + t * 8;
    int v[8];
    int tot = 0;
#pragma unroll
    for (int k = 0; k < 8; ++k) { int i = base + k; v[k] = (i < n) ? a[i] : 0; tot += v[k]; }
    __shared__ int sc[256];
    sc[t] = tot;
    __syncthreads();
    for (int off = 1; off < 256; off <<= 1) {
        int x = (t >= off) ? sc[t - off] : 0;
        __syncthreads();
        sc[t] += x;
        __syncthreads();
    }
    int excl = bsum[blockIdx.x] + sc[t] - tot;
#pragma unroll
    for (int k = 0; k < 8; ++k) { int i = base + k; if (i < n) a[i] = excl; excl += v[k]; }
    if (blockIdx.x == 0 && t == 0) a[n] = nE;
}

// ---------------------------------------------------------------------------
// Fill adjacency lists for both directions.
__global__ void fill_kernel(const void* __restrict__ es, const void* __restrict__ ed,
                            const int* __restrict__ flag,
                            int* __restrict__ cur_u, int* __restrict__ cur_m,
                            int* __restrict__ adj_u, int* __restrict__ adj_m, int nE) {
    const int is64 = *flag;
    const int stride = gridDim.x * blockDim.x;
    for (int e = blockIdx.x * blockDim.x + threadIdx.x; e < nE; e += stride) {
        int s = load_idx(es, e, is64);
        int d = load_idx(ed, e, is64);
        adj_m[atomicAdd(&cur_m[d], 1)] = s;   // movie <- its user neighbors
        adj_u[atomicAdd(&cur_u[s], 1)] = d;   // user  <- its movie neighbors
    }
}

// ---------------------------------------------------------------------------
// Fused mean-aggregate (gather via CSR) + SAGE transform.
// out[i,:] = opt_relu( mean_{s in adj[i]} xsrc[s,:] @ Wl + bl + xdst[i,:] @ Wr )
// One wave per node, lane = feature dim. Safe for xdst == out (own-row
// read-before-write within the wave; gathers never touch xdst).
template <int RELU>
__global__ void gather_node_kernel(const float* __restrict__ xsrc,
                                   const float* __restrict__ xdst,
                                   const int* __restrict__ rowptr,
                                   const int* __restrict__ adj,
                                   const float* __restrict__ Wl,
                                   const float* __restrict__ bl,
                                   const float* __restrict__ Wr,
                                   float* __restrict__ out, int n) {
    __shared__ float sW[2][DIM * DIM];
    for (int i = threadIdx.x; i < DIM * DIM; i += blockDim.x) {
        sW[0][i] = Wl[i];
        sW[1][i] = Wr[i];
    }
    __syncthreads();
    const int lane = threadIdx.x & 63;
    const int wib  = threadIdx.x >> 6;
    const int wpb  = blockDim.x >> 6;
    const float bias = bl[lane];
    for (int i = blockIdx.x * wpb + wib; i < n; i += gridDim.x * wpb) {
        const int r0 = rowptr[i], r1 = rowptr[i + 1];
        float a = 0.0f;
        for (int j = r0; j < r1; j += 64) {
            int m = r1 - j; if (m > 64) m = 64;
            int idx = (lane < m) ? adj[j + lane] : 0;
#pragma unroll 4
            for (int t = 0; t < m; ++t) {
                int s = __shfl(idx, t);
                a += xsrc[(size_t)s * DIM + lane];
            }
        }
        a *= 1.0f / fmaxf((float)(r1 - r0), 1.0f);
        float xr = xdst[(size_t)i * DIM + lane];
        float acc = bias;
#pragma unroll
        for (int k = 0; k < DIM; ++k) {
            acc += __shfl(a, k)  * sW[0][k * DIM + lane];
            acc += __shfl(xr, k) * sW[1][k * DIM + lane];
        }
        if (RELU) acc = fmaxf(acc, 0.0f);
        out[(size_t)i * DIM + lane] = acc;
    }
}

// ---------------------------------------------------------------------------
extern "C" void kernel_launch(void* const* d_in, const int* in_sizes, int n_in,
                              void* d_out, int out_size, void* d_ws, size_t ws_size,
                              hipStream_t stream) {
    const float* x_user  = (const float*)d_in[0];
    const float* x_movie = (const float*)d_in[1];
    const void*  e_src   = d_in[2];
    const void*  e_dst   = d_in[3];
    const float* W1_um_l = (const float*)d_in[4];
    const float* W1_um_r = (const float*)d_in[5];
    const float* W1_mu_l = (const float*)d_in[6];
    const float* W1_mu_r = (const float*)d_in[7];
    const float* W2_um_l = (const float*)d_in[8];
    const float* W2_um_r = (const float*)d_in[9];
    const float* W2_mu_l = (const float*)d_in[10];
    const float* W2_mu_r = (const float*)d_in[11];
    const float* b1_um = (const float*)d_in[12];
    const float* b1_mu = (const float*)d_in[13];
    const float* b2_um = (const float*)d_in[14];
    const float* b2_mu = (const float*)d_in[15];
    const int nE = in_sizes[2];

    // workspace carve-up (256B aligned)
    char* ws = (char*)d_ws;
    size_t off = 0;
    auto carve = [&](size_t bytes) {
        void* p = ws + off;
        off += (bytes + 255) & ~(size_t)255;
        return p;
    };
    int*   flag   = (int*)carve(4);
    int*   rp_u   = (int*)carve(((size_t)NU + 1) * 4);  // degrees -> rowptr
    int*   rp_m   = (int*)carve(((size_t)NM + 1) * 4);
    int*   cur_u  = (int*)carve((size_t)NU * 4);
    int*   cur_m  = (int*)carve((size_t)NM * 4);
    int*   bsum_u = (int*)carve(128 * 4);
    int*   bsum_m = (int*)carve(128 * 4);
    int*   adj_u  = (int*)carve((size_t)nE * 4);
    int*   adj_m  = (int*)carve((size_t)nE * 4);
    float* m1     = (float*)carve((size_t)NM * DIM * 4);

    // u1 lives in d_out's u2 slot (overwritten row-in-place by u2 pass)
    float* u2 = (float*)d_out;                    // [NU,64]
    float* m2 = (float*)d_out + (size_t)NU * DIM; // [NM,64]
    float* u1 = u2;

    // ---- build CSR (both directions) ----
    hipMemsetAsync(rp_u, 0, ((size_t)NU + 1) * 4, stream);
    hipMemsetAsync(rp_m, 0, ((size_t)NM + 1) * 4, stream);
    detect_idx_kernel<<<1, 256, 0, stream>>>((const unsigned int*)e_src, flag);

    const int EB = 2048;  // edge-parallel blocks
    count_kernel<<<EB, 256, 0, stream>>>(e_src, e_dst, flag, rp_u, rp_m, nE);

    const int nbU = (NU + SCAN_CHUNK - 1) / SCAN_CHUNK;
    const int nbM = (NM + SCAN_CHUNK - 1) / SCAN_CHUNK;
    scan_block_sums<<<nbU, 256, 0, stream>>>(rp_u, bsum_u, NU);
    scan_block_sums<<<nbM, 256, 0, stream>>>(rp_m, bsum_m, NM);
    scan_bsum<<<1, 64, 0, stream>>>(bsum_u, nbU);
    scan_bsum<<<1, 64, 0, stream>>>(bsum_m, nbM);
    scan_apply<<<nbU, 256, 0, stream>>>(rp_u, bsum_u, NU, nE);
    scan_apply<<<nbM, 256, 0, stream>>>(rp_m, bsum_m, NM, nE);

    hipMemcpyAsync(cur_u, rp_u, (size_t)NU * 4, hipMemcpyDeviceToDevice, stream);
    hipMemcpyAsync(cur_m, rp_m, (size_t)NM * 4, hipMemcpyDeviceToDevice, stream);
    fill_kernel<<<EB, 256, 0, stream>>>(e_src, e_dst, flag, cur_u, cur_m, adj_u, adj_m, nE);

    // ---- layer 1 (fused aggregate + transform + relu) ----
    int nbm = (NM + 3) / 4; if (nbm > 25000) nbm = 25000;
    int nbu = (NU + 3) / 4; if (nbu > 50000) nbu = 50000;
    gather_node_kernel<1><<<nbm, 256, 0, stream>>>(x_user,  x_movie, rp_m, adj_m,
                                                   W1_um_l, b1_um, W1_um_r, m1, NM);
    gather_node_kernel<1><<<nbu, 256, 0, stream>>>(x_movie, x_user,  rp_u, adj_u,
                                                   W1_mu_l, b1_mu, W1_mu_r, u1, NU);

    // ---- layer 2 ----
    // m2 gathers u1 (intact) with xdst=m1 (ws) -> writes d_out m2 slot
    gather_node_kernel<0><<<nbm, 256, 0, stream>>>(u1, m1, rp_m, adj_m,
                                                   W2_um_l, b2_um, W2_um_r, m2, NM);
    // u2 gathers m1 (ws, intact) with xdst=u1 -> overwrites u1 rows in place
    gather_node_kernel<0><<<nbu, 256, 0, stream>>>(m1, u1, rp_u, adj_u,
                                                   W2_mu_l, b2_mu, W2_mu_r, u2, NU);
}

// Round 3
// 2467.869 us; speedup vs baseline: 1.3681x; 1.3681x over previous
//
#include <hip/hip_runtime.h>
#include <stdint.h>

#define NU 200000
#define NM 100000
#define DIM 64
#define SCAN_CHUNK 2048

// ---------------------------------------------------------------------------
// Detect whether edge index arrays are int64 or int32.
__global__ void detect_idx_kernel(const unsigned int* __restrict__ words,
                                  int* __restrict__ flag) {
    __shared__ int nz;
    if (threadIdx.x == 0) nz = 0;
    __syncthreads();
    for (int i = threadIdx.x; i < 2048; i += blockDim.x)
        if (words[2 * i + 1] != 0u) nz = 1;
    __syncthreads();
    if (threadIdx.x == 0) *flag = (nz == 0) ? 1 : 0;   // 1 => int64
}

__device__ __forceinline__ int load_idx(const void* __restrict__ p, int e, int is64) {
    if (is64) return (int)((const long long*)p)[e];
    return ((const int*)p)[e];
}

// ---------------------------------------------------------------------------
__global__ void count_kernel(const void* __restrict__ es, const void* __restrict__ ed,
                             const int* __restrict__ flag,
                             int* __restrict__ deg_u, int* __restrict__ deg_m, int nE) {
    const int is64 = *flag;
    const int stride = gridDim.x * blockDim.x;
    for (int e = blockIdx.x * blockDim.x + threadIdx.x; e < nE; e += stride) {
        int s = load_idx(es, e, is64);
        int d = load_idx(ed, e, is64);
        atomicAdd(&deg_u[s], 1);
        atomicAdd(&deg_m[d], 1);
    }
}

// ---------------------------------------------------------------------------
// Exclusive scan over n ints, 3 phases (chunk = 2048 = 256 thr x 8).
__global__ void scan_block_sums(const int* __restrict__ a, int* __restrict__ bsum, int n) {
    int base = blockIdx.x * SCAN_CHUNK + threadIdx.x * 8;
    int tot = 0;
#pragma unroll
    for (int k = 0; k < 8; ++k) { int i = base + k; if (i < n) tot += a[i]; }
    __shared__ int sc[256];
    sc[threadIdx.x] = tot;
    __syncthreads();
    for (int off = 128; off > 0; off >>= 1) {
        if (threadIdx.x < off) sc[threadIdx.x] += sc[threadIdx.x + off];
        __syncthreads();
    }
    if (threadIdx.x == 0) bsum[blockIdx.x] = sc[0];
}

__global__ void scan_bsum(int* __restrict__ bsum, int nb) {
    if (blockIdx.x == 0 && threadIdx.x == 0) {
        int acc = 0;
        for (int i = 0; i < nb; ++i) { int v = bsum[i]; bsum[i] = acc; acc += v; }
    }
}

__global__ void scan_apply(int* __restrict__ a, const int* __restrict__ bsum, int n, int nE) {
    const int t = threadIdx.x;
    int base = blockIdx.x * SCAN_CHUNK + t * 8;
    int v[8];
    int tot = 0;
#pragma unroll
    for (int k = 0; k < 8; ++k) { int i = base + k; v[k] = (i < n) ? a[i] : 0; tot += v[k]; }
    __shared__ int sc[256];
    sc[t] = tot;
    __syncthreads();
    for (int off = 1; off < 256; off <<= 1) {
        int x = (t >= off) ? sc[t - off] : 0;
        __syncthreads();
        sc[t] += x;
        __syncthreads();
    }
    int excl = bsum[blockIdx.x] + sc[t] - tot;
#pragma unroll
    for (int k = 0; k < 8; ++k) { int i = base + k; if (i < n) a[i] = excl; excl += v[k]; }
    if (blockIdx.x == 0 && t == 0) a[n] = nE;
}

// ---------------------------------------------------------------------------
__global__ void fill_kernel(const void* __restrict__ es, const void* __restrict__ ed,
                            const int* __restrict__ flag,
                            int* __restrict__ cur_u, int* __restrict__ cur_m,
                            int* __restrict__ adj_u, int* __restrict__ adj_m, int nE) {
    const int is64 = *flag;
    const int stride = gridDim.x * blockDim.x;
    for (int e = blockIdx.x * blockDim.x + threadIdx.x; e < nE; e += stride) {
        int s = load_idx(es, e, is64);
        int d = load_idx(ed, e, is64);
        adj_m[atomicAdd(&cur_m[d], 1)] = s;
        adj_u[atomicAdd(&cur_u[s], 1)] = d;
    }
}

// ---------------------------------------------------------------------------
// Fused mean-aggregate (gather via CSR) + SAGE transform.
// Wave layout for the gather: lane = (neighbor slot = lane>>4, dim quarter =
// lane&15 as float4). Per 4 neighbors: 1 adj read + 1 dwordx4 load + 1 f4 add
// -> no DS ops in the gather loop, 1KB per vmem instr, high MLP.
// Safe for xdst == out (own-row read-before-write within the wave).
template <int RELU>
__global__ __launch_bounds__(512) void
gather_node_kernel(const float* __restrict__ xsrc,
                   const float* __restrict__ xdst,
                   const int* __restrict__ rowptr,
                   const int* __restrict__ adj,
                   const float* __restrict__ Wl,
                   const float* __restrict__ bl,
                   const float* __restrict__ Wr,
                   float* __restrict__ out, int n) {
    __shared__ float sW[2][DIM * DIM];
    for (int i = threadIdx.x; i < DIM * DIM; i += blockDim.x) {
        sW[0][i] = Wl[i];
        sW[1][i] = Wr[i];
    }
    __syncthreads();
    const int lane = threadIdx.x & 63;
    const int wib  = threadIdx.x >> 6;     // wave in block (0..7)
    const int wpb  = blockDim.x >> 6;      // 8
    const int grp  = lane >> 4;            // neighbor slot 0..3
    const int col  = lane & 15;            // float4 column
    const float bias = bl[lane];
    for (int i = blockIdx.x * wpb + wib; i < n; i += gridDim.x * wpb) {
        const int r0 = rowptr[i], r1 = rowptr[i + 1];
        float4 acc = make_float4(0.f, 0.f, 0.f, 0.f);
#pragma unroll 2
        for (int j = r0 + grp; j < r1; j += 4) {
            const int s = adj[j];
            const float4 v = reinterpret_cast<const float4*>(xsrc + (size_t)s * DIM)[col];
            acc.x += v.x; acc.y += v.y; acc.z += v.z; acc.w += v.w;
        }
        // butterfly over the two neighbor-group bits -> every lane holds the
        // full sum for its float4 column
        acc.x += __shfl_xor(acc.x, 16); acc.y += __shfl_xor(acc.y, 16);
        acc.z += __shfl_xor(acc.z, 16); acc.w += __shfl_xor(acc.w, 16);
        acc.x += __shfl_xor(acc.x, 32); acc.y += __shfl_xor(acc.y, 32);
        acc.z += __shfl_xor(acc.z, 32); acc.w += __shfl_xor(acc.w, 32);
        const float inv = 1.0f / fmaxf((float)(r1 - r0), 1.0f);
        const float a0 = acc.x * inv, a1 = acc.y * inv, a2 = acc.z * inv, a3 = acc.w * inv;
        const float xr = xdst[(size_t)i * DIM + lane];
        float o = bias;
#pragma unroll
        for (int k = 0; k < 16; ++k) {
            o += __shfl(a0, k) * sW[0][(4 * k + 0) * DIM + lane];
            o += __shfl(a1, k) * sW[0][(4 * k + 1) * DIM + lane];
            o += __shfl(a2, k) * sW[0][(4 * k + 2) * DIM + lane];
            o += __shfl(a3, k) * sW[0][(4 * k + 3) * DIM + lane];
        }
#pragma unroll
        for (int k = 0; k < 64; ++k)
            o += __shfl(xr, k) * sW[1][k * DIM + lane];
        if (RELU) o = fmaxf(o, 0.0f);
        out[(size_t)i * DIM + lane] = o;
    }
}

// ---------------------------------------------------------------------------
extern "C" void kernel_launch(void* const* d_in, const int* in_sizes, int n_in,
                              void* d_out, int out_size, void* d_ws, size_t ws_size,
                              hipStream_t stream) {
    const float* x_user  = (const float*)d_in[0];
    const float* x_movie = (const float*)d_in[1];
    const void*  e_src   = d_in[2];
    const void*  e_dst   = d_in[3];
    const float* W1_um_l = (const float*)d_in[4];
    const float* W1_um_r = (const float*)d_in[5];
    const float* W1_mu_l = (const float*)d_in[6];
    const float* W1_mu_r = (const float*)d_in[7];
    const float* W2_um_l = (const float*)d_in[8];
    const float* W2_um_r = (const float*)d_in[9];
    const float* W2_mu_l = (const float*)d_in[10];
    const float* W2_mu_r = (const float*)d_in[11];
    const float* b1_um = (const float*)d_in[12];
    const float* b1_mu = (const float*)d_in[13];
    const float* b2_um = (const float*)d_in[14];
    const float* b2_mu = (const float*)d_in[15];
    const int nE = in_sizes[2];

    // workspace carve-up (256B aligned)
    char* ws = (char*)d_ws;
    size_t off = 0;
    auto carve = [&](size_t bytes) {
        void* p = ws + off;
        off += (bytes + 255) & ~(size_t)255;
        return p;
    };
    int*   flag   = (int*)carve(4);
    int*   rp_u   = (int*)carve(((size_t)NU + 1) * 4);
    int*   rp_m   = (int*)carve(((size_t)NM + 1) * 4);
    int*   cur_u  = (int*)carve((size_t)NU * 4);
    int*   cur_m  = (int*)carve((size_t)NM * 4);
    int*   bsum_u = (int*)carve(128 * 4);
    int*   bsum_m = (int*)carve(128 * 4);
    int*   adj_u  = (int*)carve((size_t)nE * 4);
    int*   adj_m  = (int*)carve((size_t)nE * 4);
    float* m1     = (float*)carve((size_t)NM * DIM * 4);

    float* u2 = (float*)d_out;                    // [NU,64]
    float* m2 = (float*)d_out + (size_t)NU * DIM; // [NM,64]
    float* u1 = u2;

    // ---- build CSR (both directions) ----
    hipMemsetAsync(rp_u, 0, ((size_t)NU + 1) * 4, stream);
    hipMemsetAsync(rp_m, 0, ((size_t)NM + 1) * 4, stream);
    detect_idx_kernel<<<1, 256, 0, stream>>>((const unsigned int*)e_src, flag);

    const int EB = 2048;
    count_kernel<<<EB, 256, 0, stream>>>(e_src, e_dst, flag, rp_u, rp_m, nE);

    const int nbU = (NU + SCAN_CHUNK - 1) / SCAN_CHUNK;
    const int nbM = (NM + SCAN_CHUNK - 1) / SCAN_CHUNK;
    scan_block_sums<<<nbU, 256, 0, stream>>>(rp_u, bsum_u, NU);
    scan_block_sums<<<nbM, 256, 0, stream>>>(rp_m, bsum_m, NM);
    scan_bsum<<<1, 64, 0, stream>>>(bsum_u, nbU);
    scan_bsum<<<1, 64, 0, stream>>>(bsum_m, nbM);
    scan_apply<<<nbU, 256, 0, stream>>>(rp_u, bsum_u, NU, nE);
    scan_apply<<<nbM, 256, 0, stream>>>(rp_m, bsum_m, NM, nE);

    hipMemcpyAsync(cur_u, rp_u, (size_t)NU * 4, hipMemcpyDeviceToDevice, stream);
    hipMemcpyAsync(cur_m, rp_m, (size_t)NM * 4, hipMemcpyDeviceToDevice, stream);
    fill_kernel<<<EB, 256, 0, stream>>>(e_src, e_dst, flag, cur_u, cur_m, adj_u, adj_m, nE);

    // ---- layer 1 (fused aggregate + transform + relu) ----
    const int nbm = (NM + 7) / 8;   // 8 nodes (waves) per block
    const int nbu = (NU + 7) / 8;
    gather_node_kernel<1><<<nbm, 512, 0, stream>>>(x_user,  x_movie, rp_m, adj_m,
                                                   W1_um_l, b1_um, W1_um_r, m1, NM);
    gather_node_kernel<1><<<nbu, 512, 0, stream>>>(x_movie, x_user,  rp_u, adj_u,
                                                   W1_mu_l, b1_mu, W1_mu_r, u1, NU);

    // ---- layer 2 ----
    gather_node_kernel<0><<<nbm, 512, 0, stream>>>(u1, m1, rp_m, adj_m,
                                                   W2_um_l, b2_um, W2_um_r, m2, NM);
    gather_node_kernel<0><<<nbu, 512, 0, stream>>>(m1, u1, rp_u, adj_u,
                                                   W2_mu_l, b2_mu, W2_mu_r, u2, NU);
}

// Round 4
// 1491.945 us; speedup vs baseline: 2.2631x; 1.6541x over previous
//
#include <hip/hip_runtime.h>
#include <stdint.h>

#define NU 200000
#define NM 100000
#define DIM 64
#define SCAN_CHUNK 2048

// ---------------------------------------------------------------------------
// Detect whether edge index arrays are int64 or int32.
__global__ void detect_idx_kernel(const unsigned int* __restrict__ words,
                                  int* __restrict__ flag) {
    __shared__ int nz;
    if (threadIdx.x == 0) nz = 0;
    __syncthreads();
    for (int i = threadIdx.x; i < 2048; i += blockDim.x)
        if (words[2 * i + 1] != 0u) nz = 1;
    __syncthreads();
    if (threadIdx.x == 0) *flag = (nz == 0) ? 1 : 0;   // 1 => int64
}

__device__ __forceinline__ int load_idx(const void* __restrict__ p, int e, int is64) {
    if (is64) return (int)((const long long*)p)[e];
    return ((const int*)p)[e];
}

// ---------------------------------------------------------------------------
__global__ void count_kernel(const void* __restrict__ es, const void* __restrict__ ed,
                             const int* __restrict__ flag,
                             int* __restrict__ deg_u, int* __restrict__ deg_m, int nE) {
    const int is64 = *flag;
    const int stride = gridDim.x * blockDim.x;
    for (int e = blockIdx.x * blockDim.x + threadIdx.x; e < nE; e += stride) {
        int s = load_idx(es, e, is64);
        int d = load_idx(ed, e, is64);
        atomicAdd(&deg_u[s], 1);
        atomicAdd(&deg_m[d], 1);
    }
}

// ---------------------------------------------------------------------------
// Exclusive scan over n ints, 3 phases (chunk = 2048 = 256 thr x 8).
__global__ void scan_block_sums(const int* __restrict__ a, int* __restrict__ bsum, int n) {
    int base = blockIdx.x * SCAN_CHUNK + threadIdx.x * 8;
    int tot = 0;
#pragma unroll
    for (int k = 0; k < 8; ++k) { int i = base + k; if (i < n) tot += a[i]; }
    __shared__ int sc[256];
    sc[threadIdx.x] = tot;
    __syncthreads();
    for (int off = 128; off > 0; off >>= 1) {
        if (threadIdx.x < off) sc[threadIdx.x] += sc[threadIdx.x + off];
        __syncthreads();
    }
    if (threadIdx.x == 0) bsum[blockIdx.x] = sc[0];
}

__global__ void scan_bsum(int* __restrict__ bsum, int nb) {
    if (blockIdx.x == 0 && threadIdx.x == 0) {
        int acc = 0;
        for (int i = 0; i < nb; ++i) { int v = bsum[i]; bsum[i] = acc; acc += v; }
    }
}

__global__ void scan_apply(int* __restrict__ a, const int* __restrict__ bsum, int n, int nE) {
    const int t = threadIdx.x;
    int base = blockIdx.x * SCAN_CHUNK + t * 8;
    int v[8];
    int tot = 0;
#pragma unroll
    for (int k = 0; k < 8; ++k) { int i = base + k; v[k] = (i < n) ? a[i] : 0; tot += v[k]; }
    __shared__ int sc[256];
    sc[t] = tot;
    __syncthreads();
    for (int off = 1; off < 256; off <<= 1) {
        int x = (t >= off) ? sc[t - off] : 0;
        __syncthreads();
        sc[t] += x;
        __syncthreads();
    }
    int excl = bsum[blockIdx.x] + sc[t] - tot;
#pragma unroll
    for (int k = 0; k < 8; ++k) { int i = base + k; if (i < n) a[i] = excl; excl += v[k]; }
    if (blockIdx.x == 0 && t == 0) a[n] = nE;
}

// ---------------------------------------------------------------------------
__global__ void fill_kernel(const void* __restrict__ es, const void* __restrict__ ed,
                            const int* __restrict__ flag,
                            int* __restrict__ cur_u, int* __restrict__ cur_m,
                            int* __restrict__ adj_u, int* __restrict__ adj_m, int nE) {
    const int is64 = *flag;
    const int stride = gridDim.x * blockDim.x;
    for (int e = blockIdx.x * blockDim.x + threadIdx.x; e < nE; e += stride) {
        int s = load_idx(es, e, is64);
        int d = load_idx(ed, e, is64);
        adj_m[atomicAdd(&cur_m[d], 1)] = s;
        adj_u[atomicAdd(&cur_u[s], 1)] = d;
    }
}

// ---------------------------------------------------------------------------
// Fused tile kernel: block = 256 threads = 4 waves, tile = 64 nodes.
// Phase 1 (gather): wave w handles nodes w*16..w*16+15 sequentially; per node
//   4 neighbors x float4 layout (grp=lane>>4, col=lane&15), butterfly reduce,
//   then grp0 writes mean into LDS rows 0..63 (transposed: row=k, col=node)
//   and grp1 loads the x_dst row and writes rows 64..127. Column-group XOR
//   swizzle (colgrp ^= (k>>2)&15) -> conflict-free scalar writes AND b128
//   reads (bank math checked both phases).
// Phase 2 (transform): C[64 nodes][64 dims] = AX[64][128] @ W[128][64] + b.
//   Thread = 4 nodes (4rq..) x 4 dims (4cq..): per k, 2x ds_read_b128 + 16 FMA.
// Safe for xdst == out: xdst reads are tile-local and precede the tile store.
template <int RELU>
__global__ __launch_bounds__(256) void
fused_tile_kernel(const float* __restrict__ xsrc,
                  const float* __restrict__ xdst,
                  const int* __restrict__ rowptr,
                  const int* __restrict__ adj,
                  const float* __restrict__ Wl,
                  const float* __restrict__ Wr,
                  const float* __restrict__ bl,
                  float* __restrict__ out, int n) {
    __shared__ float sAX[128 * 64];  // row k, col = swizzled node
    __shared__ float sW[128 * 64];   // rows 0..63 = Wl[k][:], 64..127 = Wr[k][:]

    const int tid = threadIdx.x;
    // stage weights: 2 x 4096 floats = 2 x 1024 float4, 256 threads -> 4+4 each
    {
        const float4* wl4 = (const float4*)Wl;
        const float4* wr4 = (const float4*)Wr;
        float4* sw4 = (float4*)sW;
#pragma unroll
        for (int i = 0; i < 4; ++i) {
            sw4[tid + 256 * i] = wl4[tid + 256 * i];
            sw4[1024 + tid + 256 * i] = wr4[tid + 256 * i];
        }
    }

    const int lane = tid & 63;
    const int w    = tid >> 6;      // wave 0..3
    const int grp  = lane >> 4;     // neighbor slot 0..3
    const int col  = lane & 15;     // float4 quarter 0..15
    const int base = blockIdx.x * 64;

    for (int s = 0; s < 16; ++s) {
        const int ln = w * 16 + s;   // local node 0..63
        const int i  = base + ln;
        if (i < n) {
            const int r0 = rowptr[i], r1 = rowptr[i + 1];
            float4 acc = make_float4(0.f, 0.f, 0.f, 0.f);
#pragma unroll 2
            for (int j = r0 + grp; j < r1; j += 4) {
                const int sv = adj[j];
                const float4 v = ((const float4*)(xsrc + (size_t)sv * DIM))[col];
                acc.x += v.x; acc.y += v.y; acc.z += v.z; acc.w += v.w;
            }
            acc.x += __shfl_xor(acc.x, 16); acc.y += __shfl_xor(acc.y, 16);
            acc.z += __shfl_xor(acc.z, 16); acc.w += __shfl_xor(acc.w, 16);
            acc.x += __shfl_xor(acc.x, 32); acc.y += __shfl_xor(acc.y, 32);
            acc.z += __shfl_xor(acc.z, 32); acc.w += __shfl_xor(acc.w, 32);
            // swizzled physical column for k-group == col (holds for both the
            // A rows k=4*col+jj and the X rows k=64+4*col+jj)
            const int pc = ((((ln >> 2) ^ col) << 2) | (ln & 3));
            if (grp == 0) {
                const float invd = 1.0f / fmaxf((float)(r1 - r0), 1.0f);
                sAX[(4 * col + 0) * 64 + pc] = acc.x * invd;
                sAX[(4 * col + 1) * 64 + pc] = acc.y * invd;
                sAX[(4 * col + 2) * 64 + pc] = acc.z * invd;
                sAX[(4 * col + 3) * 64 + pc] = acc.w * invd;
            } else if (grp == 1) {
                const float4 xv = ((const float4*)(xdst + (size_t)i * DIM))[col];
                sAX[(64 + 4 * col + 0) * 64 + pc] = xv.x;
                sAX[(64 + 4 * col + 1) * 64 + pc] = xv.y;
                sAX[(64 + 4 * col + 2) * 64 + pc] = xv.z;
                sAX[(64 + 4 * col + 3) * 64 + pc] = xv.w;
            }
        }
    }
    __syncthreads();

    // ---- transform ----
    const int rq = tid >> 4;   // node quad 0..15
    const int cq = tid & 15;   // dim quad 0..15
    const float4 bv = ((const float4*)bl)[cq];
    float4 a0 = bv, a1 = bv, a2 = bv, a3 = bv;   // rows = 4 nodes, cols = 4 dims
#pragma unroll 4
    for (int k = 0; k < 128; ++k) {
        const int g = (k >> 2) & 15;
        const float4 av = *(const float4*)&sAX[k * 64 + ((rq ^ g) << 2)];
        const float4 wv = *(const float4*)&sW[k * 64 + (cq << 2)];
        a0.x += av.x * wv.x; a0.y += av.x * wv.y; a0.z += av.x * wv.z; a0.w += av.x * wv.w;
        a1.x += av.y * wv.x; a1.y += av.y * wv.y; a1.z += av.y * wv.z; a1.w += av.y * wv.w;
        a2.x += av.z * wv.x; a2.y += av.z * wv.y; a2.z += av.z * wv.z; a2.w += av.z * wv.w;
        a3.x += av.w * wv.x; a3.y += av.w * wv.y; a3.z += av.w * wv.z; a3.w += av.w * wv.w;
    }
    float4 r[4] = {a0, a1, a2, a3};
#pragma unroll
    for (int i = 0; i < 4; ++i) {
        const int node = base + 4 * rq + i;
        if (node < n) {
            float4 v = r[i];
            if (RELU) {
                v.x = fmaxf(v.x, 0.f); v.y = fmaxf(v.y, 0.f);
                v.z = fmaxf(v.z, 0.f); v.w = fmaxf(v.w, 0.f);
            }
            ((float4*)(out + (size_t)node * DIM))[cq] = v;
        }
    }
}

// ---------------------------------------------------------------------------
extern "C" void kernel_launch(void* const* d_in, const int* in_sizes, int n_in,
                              void* d_out, int out_size, void* d_ws, size_t ws_size,
                              hipStream_t stream) {
    const float* x_user  = (const float*)d_in[0];
    const float* x_movie = (const float*)d_in[1];
    const void*  e_src   = d_in[2];
    const void*  e_dst   = d_in[3];
    const float* W1_um_l = (const float*)d_in[4];
    const float* W1_um_r = (const float*)d_in[5];
    const float* W1_mu_l = (const float*)d_in[6];
    const float* W1_mu_r = (const float*)d_in[7];
    const float* W2_um_l = (const float*)d_in[8];
    const float* W2_um_r = (const float*)d_in[9];
    const float* W2_mu_l = (const float*)d_in[10];
    const float* W2_mu_r = (const float*)d_in[11];
    const float* b1_um = (const float*)d_in[12];
    const float* b1_mu = (const float*)d_in[13];
    const float* b2_um = (const float*)d_in[14];
    const float* b2_mu = (const float*)d_in[15];
    const int nE = in_sizes[2];

    // workspace carve-up (256B aligned): CSR + m1 only (~44 MB)
    char* ws = (char*)d_ws;
    size_t off = 0;
    auto carve = [&](size_t bytes) {
        void* p = ws + off;
        off += (bytes + 255) & ~(size_t)255;
        return p;
    };
    int*   flag   = (int*)carve(4);
    int*   rp_u   = (int*)carve(((size_t)NU + 1) * 4);
    int*   rp_m   = (int*)carve(((size_t)NM + 1) * 4);
    int*   cur_u  = (int*)carve((size_t)NU * 4);
    int*   cur_m  = (int*)carve((size_t)NM * 4);
    int*   bsum_u = (int*)carve(128 * 4);
    int*   bsum_m = (int*)carve(128 * 4);
    int*   adj_u  = (int*)carve((size_t)nE * 4);
    int*   adj_m  = (int*)carve((size_t)nE * 4);
    float* m1     = (float*)carve((size_t)NM * DIM * 4);

    float* u2 = (float*)d_out;                    // [NU,64]; also u1 (in-place)
    float* m2 = (float*)d_out + (size_t)NU * DIM; // [NM,64]
    float* u1 = u2;

    // ---- build CSR (both directions) ----
    hipMemsetAsync(rp_u, 0, ((size_t)NU + 1) * 4, stream);
    hipMemsetAsync(rp_m, 0, ((size_t)NM + 1) * 4, stream);
    detect_idx_kernel<<<1, 256, 0, stream>>>((const unsigned int*)e_src, flag);

    const int EB = 2048;
    count_kernel<<<EB, 256, 0, stream>>>(e_src, e_dst, flag, rp_u, rp_m, nE);

    const int nbU = (NU + SCAN_CHUNK - 1) / SCAN_CHUNK;
    const int nbM = (NM + SCAN_CHUNK - 1) / SCAN_CHUNK;
    scan_block_sums<<<nbU, 256, 0, stream>>>(rp_u, bsum_u, NU);
    scan_block_sums<<<nbM, 256, 0, stream>>>(rp_m, bsum_m, NM);
    scan_bsum<<<1, 64, 0, stream>>>(bsum_u, nbU);
    scan_bsum<<<1, 64, 0, stream>>>(bsum_m, nbM);
    scan_apply<<<nbU, 256, 0, stream>>>(rp_u, bsum_u, NU, nE);
    scan_apply<<<nbM, 256, 0, stream>>>(rp_m, bsum_m, NM, nE);

    hipMemcpyAsync(cur_u, rp_u, (size_t)NU * 4, hipMemcpyDeviceToDevice, stream);
    hipMemcpyAsync(cur_m, rp_m, (size_t)NM * 4, hipMemcpyDeviceToDevice, stream);
    fill_kernel<<<EB, 256, 0, stream>>>(e_src, e_dst, flag, cur_u, cur_m, adj_u, adj_m, nE);

    // ---- fused layers ----
    const int nbm = (NM + 63) / 64;
    const int nbu = (NU + 63) / 64;
    // layer 1
    fused_tile_kernel<1><<<nbm, 256, 0, stream>>>(x_user,  x_movie, rp_m, adj_m,
                                                  W1_um_l, W1_um_r, b1_um, m1, NM);
    fused_tile_kernel<1><<<nbu, 256, 0, stream>>>(x_movie, x_user,  rp_u, adj_u,
                                                  W1_mu_l, W1_mu_r, b1_mu, u1, NU);
    // layer 2 (m2 first: reads u1 + m1; then u2 in-place over u1, reads m1)
    fused_tile_kernel<0><<<nbm, 256, 0, stream>>>(u1, m1, rp_m, adj_m,
                                                  W2_um_l, W2_um_r, b2_um, m2, NM);
    fused_tile_kernel<0><<<nbu, 256, 0, stream>>>(m1, u1, rp_u, adj_u,
                                                  W2_mu_l, W2_mu_r, b2_mu, u2, NU);
}